// Round 6
// baseline (234.039 us; speedup 1.0000x reference)
//
#include <hip/hip_runtime.h>
#include <hip/hip_bf16.h>

typedef short bf16x8 __attribute__((ext_vector_type(8)));
typedef float f32x4  __attribute__((ext_vector_type(4)));
typedef unsigned short u16;
typedef unsigned long long u64;

static __device__ __forceinline__ u16 f2bf(float f) {
    unsigned u = __float_as_uint(f);
    u += 0x7FFFu + ((u >> 16) & 1u);
    return (u16)(u >> 16);
}
static __device__ __forceinline__ float bf2f(u16 b) {
    return __uint_as_float(((unsigned)b) << 16);
}
static __device__ __forceinline__ unsigned pack2(float lo, float hi) {
    return (unsigned)f2bf(lo) | ((unsigned)f2bf(hi) << 16);
}

// ---------------------------------------------------------------------------
// W' [256 cols][128 k] bf16. W'[c][k] = W1[k][c] (c<128), W1[128+k][c-128].
// ---------------------------------------------------------------------------
__global__ void prep_w(const float* __restrict__ W1, u16* __restrict__ Wl) {
    int idx = blockIdx.x * 256 + threadIdx.x;
    if (idx >= 256 * 128) return;
    int r = idx >> 7, q = idx & 127;
    int k = (r < 128) ? r : (r - 128);
    int c = (r < 128) ? q : (q + 128);
    Wl[c * 128 + k] = f2bf(W1[idx]);
}

// ---------------------------------------------------------------------------
// Edge counting-sort by src bucket (s>>6): zero -> hist -> scan -> scatter.
// ---------------------------------------------------------------------------
__global__ void zero_hist(int* __restrict__ hist, int n) {
    int i = blockIdx.x * 256 + threadIdx.x;
    if (i < n) hist[i] = 0;
}

__global__ __launch_bounds__(256) void e_hist(
    const int* __restrict__ ei, int* __restrict__ hist, int E, int NB)
{
    __shared__ int h[2048];
    for (int i = threadIdx.x; i < NB; i += 256) h[i] = 0;
    __syncthreads();
    for (int e = blockIdx.x * 256 + threadIdx.x; e < E; e += gridDim.x * 256)
        atomicAdd(&h[ei[e] >> 6], 1);
    __syncthreads();
    for (int i = threadIdx.x; i < NB; i += 256)
        if (h[i]) atomicAdd(&hist[i], h[i]);
}

__global__ __launch_bounds__(1024) void e_scan(
    const int* __restrict__ hist, int* __restrict__ cursor, int NB)
{
    __shared__ int s[2048];
    int t = threadIdx.x;
    s[t]        = (t < NB)        ? hist[t]        : 0;
    s[t + 1024] = (t + 1024 < NB) ? hist[t + 1024] : 0;
    __syncthreads();
    for (int off = 1; off < 2048; off <<= 1) {
        int a0 = s[t]        + ((t >= off)        ? s[t - off]        : 0);
        int a1 = s[t + 1024] + ((t + 1024 >= off) ? s[t + 1024 - off] : 0);
        __syncthreads();
        s[t] = a0; s[t + 1024] = a1;
        __syncthreads();
    }
    if (t < NB)        cursor[t]        = (t == 0) ? 0 : s[t - 1];
    if (t + 1024 < NB) cursor[t + 1024] = s[t + 1023];
}

__global__ __launch_bounds__(256) void e_scatter(
    const int* __restrict__ ei, int* __restrict__ cursor,
    u64* __restrict__ se, int E)
{
    for (int e = blockIdx.x * 256 + threadIdx.x; e < E; e += gridDim.x * 256) {
        int s = ei[e], d = ei[E + e];
        int pos = atomicAdd(&cursor[s >> 6], 1);
        se[pos] = (u64)s | ((u64)d << 17) | ((u64)e << 34);
    }
}

// ---------------------------------------------------------------------------
// Persistent GEMM: P[m][c]=sum_k z*W' + b1 (c<128), Q[m][c-128] otherwise.
// ---------------------------------------------------------------------------
#define BM 64
__global__ __launch_bounds__(256, 3) void node_gemm(
    const float* __restrict__ z, const u16* __restrict__ Wl,
    const float* __restrict__ b1,
    u16* __restrict__ P, u16* __restrict__ Q, int M, int ntiles)
{
    __shared__ char As[BM * 256];
    __shared__ char Cb[BM * 512];
    const int tid  = threadIdx.x;
    const int lane = tid & 63;
    const int wave = tid >> 6;
    const int g    = lane >> 4;
    const int ln   = lane & 15;
    const int c0   = wave * 64;

    int t = blockIdx.x;
    if (t >= ntiles) return;

    bf16x8 af[4][4];
    #pragma unroll
    for (int ks = 0; ks < 4; ++ks)
        #pragma unroll
        for (int ci = 0; ci < 4; ++ci)
            af[ks][ci] = *(const bf16x8*)(Wl + (c0 + ci * 16 + ln) * 128 + ks * 32 + g * 8);

    float4 bias[4];
    #pragma unroll
    for (int ci = 0; ci < 4; ++ci) {
        int col = c0 + ci * 16 + g * 4;
        bias[ci] = (col < 128) ? *(const float4*)(b1 + col)
                               : make_float4(0.f, 0.f, 0.f, 0.f);
    }

    float4 r[8];
    {
        int m0 = t * BM;
        #pragma unroll
        for (int i = 0; i < 8; ++i) {
            int ci = tid + i * 256, row = ci >> 5, c4 = ci & 31;
            r[i] = make_float4(0.f, 0.f, 0.f, 0.f);
            if (m0 + row < M)
                r[i] = *(const float4*)(z + (size_t)(m0 + row) * 128 + c4 * 4);
        }
        #pragma unroll
        for (int i = 0; i < 8; ++i) {
            int ci = tid + i * 256, row = ci >> 5, c4 = ci & 31;
            ushort4 b;
            b.x = f2bf(r[i].x); b.y = f2bf(r[i].y);
            b.z = f2bf(r[i].z); b.w = f2bf(r[i].w);
            *(ushort4*)(As + row * 256 + ((c4 * 8) ^ ((row & 7) << 4))) = b;
        }
    }
    __syncthreads();

    while (true) {
        int next = t + gridDim.x;
        bool have = (next < ntiles);

        if (have) {
            int m0 = next * BM;
            #pragma unroll
            for (int i = 0; i < 8; ++i) {
                int ci = tid + i * 256, row = ci >> 5, c4 = ci & 31;
                r[i] = make_float4(0.f, 0.f, 0.f, 0.f);
                if (m0 + row < M)
                    r[i] = *(const float4*)(z + (size_t)(m0 + row) * 128 + c4 * 4);
            }
        }

        f32x4 acc[4][4];
        #pragma unroll
        for (int mf = 0; mf < 4; ++mf)
            #pragma unroll
            for (int ci = 0; ci < 4; ++ci)
                acc[mf][ci] = (f32x4){0.f, 0.f, 0.f, 0.f};
        #pragma unroll
        for (int ks = 0; ks < 4; ++ks) {
            #pragma unroll
            for (int mf = 0; mf < 4; ++mf) {
                int row  = mf * 16 + ln;
                int byte = row * 256 + ((ks * 64 + g * 16) ^ ((row & 7) << 4));
                bf16x8 b = *(const bf16x8*)(As + byte);
                #pragma unroll
                for (int ci = 0; ci < 4; ++ci)
                    acc[mf][ci] = __builtin_amdgcn_mfma_f32_16x16x32_bf16(
                        af[ks][ci], b, acc[mf][ci], 0, 0, 0);
            }
        }

        #pragma unroll
        for (int mf = 0; mf < 4; ++mf) {
            int node = mf * 16 + ln;
            #pragma unroll
            for (int ci = 0; ci < 4; ++ci) {
                int col = c0 + ci * 16 + g * 4;
                uint2 w;
                w.x = pack2(acc[mf][ci][0] + bias[ci].x,
                            acc[mf][ci][1] + bias[ci].y);
                w.y = pack2(acc[mf][ci][2] + bias[ci].z,
                            acc[mf][ci][3] + bias[ci].w);
                *(uint2*)(Cb + node * 512 + ((col * 2) ^ ((node & 7) << 4))) = w;
            }
        }
        __syncthreads();

        {
            int m0 = t * BM;
            int chunk = tid & 31;          // 16B chunk in 512B row
            int nb    = tid >> 5;
            #pragma unroll
            for (int it = 0; it < 8; ++it) {
                int node = it * 8 + nb;
                uint4 v = *(const uint4*)(Cb + node * 512 +
                                          ((chunk * 16) ^ ((node & 7) << 4)));
                if (m0 + node < M) {
                    u16* dst = (chunk < 16)
                        ? (P + (size_t)(m0 + node) * 128 + chunk * 8)
                        : (Q + (size_t)(m0 + node) * 128 + (chunk - 16) * 8);
                    *(uint4*)dst = v;
                }
            }
        }

        if (have) {
            #pragma unroll
            for (int i = 0; i < 8; ++i) {
                int ci = tid + i * 256, row = ci >> 5, c4 = ci & 31;
                ushort4 b;
                b.x = f2bf(r[i].x); b.y = f2bf(r[i].y);
                b.z = f2bf(r[i].z); b.w = f2bf(r[i].w);
                *(ushort4*)(As + row * 256 + ((c4 * 8) ^ ((row & 7) << 4))) = b;
            }
        } else {
            break;
        }
        __syncthreads();
        t = next;
    }
}

// ---------------------------------------------------------------------------
// Edge kernel over SORTED edges. 64 edges per block (16 groups x 4 edges).
// XCD-swizzled blocks: each XCD owns a contiguous sorted range -> P gathers
// are L2-local. Grid padded to a multiple of 8 so the swizzle is bijective.
// ---------------------------------------------------------------------------
__global__ __launch_bounds__(256) void edge_mlp_sorted(
    const u64* __restrict__ se,    // packed (e<<34)|(d<<17)|s, bucket-sorted
    const u16* __restrict__ P, const u16* __restrict__ Q,
    const float* __restrict__ W2, const float* __restrict__ b2,
    float* __restrict__ out, int E)
{
    int cpx = gridDim.x >> 3;      // gridDim.x is a multiple of 8
    int swz = (blockIdx.x & 7) * cpx + (blockIdx.x >> 3);
    int pos0 = swz * 64 + (threadIdx.x >> 4) * 4;   // 64 edges per block
    int sub  = threadIdx.x & 15;
    if (pos0 >= E) return;

    float4 w2a = *(const float4*)(W2 + sub * 8);
    float4 w2b = *(const float4*)(W2 + sub * 8 + 4);
    float ww[8] = {w2a.x, w2a.y, w2a.z, w2a.w, w2b.x, w2b.y, w2b.z, w2b.w};
    float bias = b2[0];

    if (pos0 + 3 < E) {
        ulonglong2 A = *(const ulonglong2*)(se + pos0);
        ulonglong2 B = *(const ulonglong2*)(se + pos0 + 2);
        u64 v[4] = {A.x, A.y, B.x, B.y};
        float a[4];
        uint4 pv[4], qv[4];
        #pragma unroll
        for (int k = 0; k < 4; ++k) {
            unsigned s = (unsigned)(v[k] & 0x1FFFF);
            unsigned d = (unsigned)((v[k] >> 17) & 0x1FFFF);
            pv[k] = *(const uint4*)(P + (size_t)s * 128 + sub * 8);
            qv[k] = *(const uint4*)(Q + (size_t)d * 128 + sub * 8);
        }
        #pragma unroll
        for (int k = 0; k < 4; ++k) {
            const u16* pu = (const u16*)&pv[k];
            const u16* qu = (const u16*)&qv[k];
            float acc = 0.f;
            #pragma unroll
            for (int j = 0; j < 8; ++j)
                acc = fmaf(fmaxf(bf2f(pu[j]) + bf2f(qu[j]), 0.f), ww[j], acc);
            a[k] = acc;
        }
        #pragma unroll
        for (int m = 1; m < 16; m <<= 1) {
            a[0] += __shfl_xor(a[0], m);
            a[1] += __shfl_xor(a[1], m);
            a[2] += __shfl_xor(a[2], m);
            a[3] += __shfl_xor(a[3], m);
        }
        if (sub == 0) {
            #pragma unroll
            for (int k = 0; k < 4; ++k)
                out[(unsigned)(v[k] >> 34)] = a[k] + bias;
        }
    } else {
        for (int k = 0; k < 4; ++k) {
            int pos = pos0 + k;
            if (pos >= E) break;
            u64 v = se[pos];
            unsigned s = (unsigned)(v & 0x1FFFF);
            unsigned d = (unsigned)((v >> 17) & 0x1FFFF);
            uint4 p = *(const uint4*)(P + (size_t)s * 128 + sub * 8);
            uint4 q = *(const uint4*)(Q + (size_t)d * 128 + sub * 8);
            const u16* pu = (const u16*)&p; const u16* qu = (const u16*)&q;
            float acc = 0.f;
            #pragma unroll
            for (int j = 0; j < 8; ++j)
                acc = fmaf(fmaxf(bf2f(pu[j]) + bf2f(qu[j]), 0.f), ww[j], acc);
            #pragma unroll
            for (int m = 1; m < 16; m <<= 1) acc += __shfl_xor(acc, m);
            if (sub == 0) out[(unsigned)(v >> 34)] = acc + bias;
        }
    }
}

// Fallback (no workspace for sort): unsorted edge kernel on split P/Q.
__global__ __launch_bounds__(256) void edge_mlp_flat(
    const int* __restrict__ ei,
    const u16* __restrict__ P, const u16* __restrict__ Q,
    const float* __restrict__ W2, const float* __restrict__ b2,
    float* __restrict__ out, int E)
{
    int gid = blockIdx.x * 256 + threadIdx.x;
    int e0  = (gid >> 4) * 4;
    int sub = gid & 15;
    if (e0 >= E) return;
    float4 w2a = *(const float4*)(W2 + sub * 8);
    float4 w2b = *(const float4*)(W2 + sub * 8 + 4);
    float ww[8] = {w2a.x, w2a.y, w2a.z, w2a.w, w2b.x, w2b.y, w2b.z, w2b.w};
    float bias = b2[0];
    for (int k = 0; k < 4; ++k) {
        int e = e0 + k;
        if (e >= E) break;
        int sn = ei[e], dn = ei[E + e];
        uint4 p = *(const uint4*)(P + (size_t)sn * 128 + sub * 8);
        uint4 q = *(const uint4*)(Q + (size_t)dn * 128 + sub * 8);
        const u16* pu = (const u16*)&p; const u16* qu = (const u16*)&q;
        float acc = 0.f;
        #pragma unroll
        for (int j = 0; j < 8; ++j)
            acc = fmaf(fmaxf(bf2f(pu[j]) + bf2f(qu[j]), 0.f), ww[j], acc);
        #pragma unroll
        for (int m = 1; m < 16; m <<= 1) acc += __shfl_xor(acc, m);
        if (sub == 0) out[e] = acc + bias;
    }
}

// ---------------------------------------------------------------------------
extern "C" void kernel_launch(void* const* d_in, const int* in_sizes, int n_in,
                              void* d_out, int out_size, void* d_ws, size_t ws_size,
                              hipStream_t stream) {
    const float* z  = (const float*)d_in[0];
    const int*   ei = (const int*)d_in[1];
    const float* W1 = (const float*)d_in[2];
    const float* b1 = (const float*)d_in[3];
    const float* W2 = (const float*)d_in[4];
    const float* b2 = (const float*)d_in[5];
    float* out = (float*)d_out;

    const int M = in_sizes[0] / 128;   // 100000 nodes
    const int E = in_sizes[1] / 2;     // 640000 edges
    const int NB = (M + 63) >> 6;      // 1563 src buckets

    char* ws = (char*)d_ws;
    u16* Wl     = (u16*)ws;                              // 64 KB
    int* hist   = (int*)(ws + 65536);                    // 8 KB
    int* cursor = (int*)(ws + 73728);                    // 8 KB
    size_t pOff = 81920;
    size_t pqBytes = (size_t)M * 128 * 2;
    u16* P = (u16*)(ws + pOff);
    u16* Q = (u16*)(ws + pOff + pqBytes);
    u64* se = (u64*)(ws + pOff + 2 * pqBytes);
    size_t need = pOff + 2 * pqBytes + (size_t)E * 8;
    bool do_sort = (ws_size >= need) && (NB <= 2048) && (M < (1 << 17)) &&
                   (E < (1 << 20));

    hipLaunchKernelGGL(prep_w, dim3(128), dim3(256), 0, stream, W1, Wl);

    if (do_sort) {
        hipLaunchKernelGGL(zero_hist, dim3((NB + 255) / 256), dim3(256), 0,
                           stream, hist, NB);
        hipLaunchKernelGGL(e_hist, dim3(256), dim3(256), 0, stream,
                           ei, hist, E, NB);
        hipLaunchKernelGGL(e_scan, dim3(1), dim3(1024), 0, stream,
                           hist, cursor, NB);
        hipLaunchKernelGGL(e_scatter, dim3(256), dim3(256), 0, stream,
                           ei, cursor, se, E);
    }

    int ntiles = (M + BM - 1) / BM;
    int gb = ntiles < 768 ? ntiles : 768;
    hipLaunchKernelGGL(node_gemm, dim3(gb), dim3(256), 0, stream,
                       z, Wl, b1, P, Q, M, ntiles);

    if (do_sort) {
        int nwg = (E + 63) / 64;         // 64 edges per block
        nwg = (nwg + 7) & ~7;            // multiple of 8: bijective XCD swizzle
        hipLaunchKernelGGL(edge_mlp_sorted, dim3(nwg), dim3(256), 0, stream,
                           se, P, Q, W2, b2, out, E);
    } else {
        int eb = ((E + 3) / 4 * 16 + 255) / 256;
        hipLaunchKernelGGL(edge_mlp_flat, dim3(eb), dim3(256), 0, stream,
                           ei, P, Q, W2, b2, out, E);
    }
}

// Round 7
// 71.796 us; speedup vs baseline: 3.2598x; 3.2598x over previous
//
#include <hip/hip_runtime.h>
#include <hip/hip_bf16.h>

typedef short bf16x8 __attribute__((ext_vector_type(8)));
typedef float f32x4  __attribute__((ext_vector_type(4)));
typedef unsigned short u16;

// float -> bf16 round-to-nearest-even
static __device__ __forceinline__ u16 f2bf(float f) {
    unsigned u = __float_as_uint(f);
    u += 0x7FFFu + ((u >> 16) & 1u);
    return (u16)(u >> 16);
}
static __device__ __forceinline__ float bf2f(u16 b) {
    return __uint_as_float(((unsigned)b) << 16);
}
static __device__ __forceinline__ unsigned pack2(float lo, float hi) {
    return (unsigned)f2bf(lo) | ((unsigned)f2bf(hi) << 16);
}

// ---------------------------------------------------------------------------
// Persistent GEMM: PQ[m][c] = sum_k z[m][k]*W'[c][k] + b1[c] (c<128), where
// W'[c][k] = W1[k][c] (c<128) or W1[128+k][c-128]. bf16 out, fp32 accum.
// BM=64 rows/tile, grid 512 persistent, (256,2): VGPR cap 256 -> NO spill
// (R6 lesson: (256,3) capped at ~170 < ~176 live -> scratch thrash, 5x).
// W' fragments built from W1 directly in the prologue (loop-invariant).
// C staged through LDS -> 512B-contiguous coalesced stores (R3 lesson).
// ---------------------------------------------------------------------------
#define BM 64
__global__ __launch_bounds__(256, 2) void node_gemm(
    const float* __restrict__ z,   // [M][128] fp32
    const float* __restrict__ W1,  // [256][128] fp32
    const float* __restrict__ b1,  // [128]
    u16*         __restrict__ PQ,  // [M][256] bf16
    int M, int ntiles)
{
    __shared__ char As[BM * 256];   // 16 KB: 64 rows x 128 bf16, swizzled
    __shared__ char Cb[BM * 512];   // 32 KB: 64 rows x 256 bf16, swizzled
    const int tid  = threadIdx.x;
    const int lane = tid & 63;
    const int wave = tid >> 6;
    const int g    = lane >> 4;     // k-group 0..3
    const int ln   = lane & 15;
    const int c0   = wave * 64;     // this wave's W'-column slice

    int t = blockIdx.x;
    if (t >= ntiles) return;

    // ---- tile-invariant: W' fragments (from W1 directly) and bias ----
    bf16x8 af[4][4];   // [ks][ci]
    #pragma unroll
    for (int ci = 0; ci < 4; ++ci) {
        int c = c0 + ci * 16 + ln;
        const float* src = (c < 128) ? (W1 + c) : (W1 + 128 * 128 + (c - 128));
        #pragma unroll
        for (int ks = 0; ks < 4; ++ks) {
            bf16x8 v;
            #pragma unroll
            for (int j = 0; j < 8; ++j)
                v[j] = (short)f2bf(src[(ks * 32 + g * 8 + j) * 128]);
            af[ks][ci] = v;
        }
    }

    float4 bias[4];
    #pragma unroll
    for (int ci = 0; ci < 4; ++ci) {
        int col = c0 + ci * 16 + g * 4;
        bias[ci] = (col < 128) ? *(const float4*)(b1 + col)
                               : make_float4(0.f, 0.f, 0.f, 0.f);
    }

    float4 r[8];       // z staging regs: 8 float4 chunks (64 rows x 32 ch)

    // ---- prologue: load + stage tile t ----
    {
        int m0 = t * BM;
        #pragma unroll
        for (int i = 0; i < 8; ++i) {
            int ci = tid + i * 256, row = ci >> 5, c4 = ci & 31;
            r[i] = make_float4(0.f, 0.f, 0.f, 0.f);
            if (m0 + row < M)
                r[i] = *(const float4*)(z + (size_t)(m0 + row) * 128 + c4 * 4);
        }
        #pragma unroll
        for (int i = 0; i < 8; ++i) {
            int ci = tid + i * 256, row = ci >> 5, c4 = ci & 31;
            ushort4 b;
            b.x = f2bf(r[i].x); b.y = f2bf(r[i].y);
            b.z = f2bf(r[i].z); b.w = f2bf(r[i].w);
            *(ushort4*)(As + row * 256 + ((c4 * 8) ^ ((row & 7) << 4))) = b;
        }
    }
    __syncthreads();

    while (true) {
        int next = t + gridDim.x;
        bool have = (next < ntiles);

        // ---- issue next tile's z loads (stay in flight through MFMA) ----
        if (have) {
            int m0 = next * BM;
            #pragma unroll
            for (int i = 0; i < 8; ++i) {
                int ci = tid + i * 256, row = ci >> 5, c4 = ci & 31;
                r[i] = make_float4(0.f, 0.f, 0.f, 0.f);
                if (m0 + row < M)
                    r[i] = *(const float4*)(z + (size_t)(m0 + row) * 128 + c4 * 4);
            }
        }

        // ---- MFMA tile t from As ----
        f32x4 acc[4][4];   // [mf][ci]
        #pragma unroll
        for (int mf = 0; mf < 4; ++mf)
            #pragma unroll
            for (int ci = 0; ci < 4; ++ci)
                acc[mf][ci] = (f32x4){0.f, 0.f, 0.f, 0.f};
        #pragma unroll
        for (int ks = 0; ks < 4; ++ks) {
            #pragma unroll
            for (int mf = 0; mf < 4; ++mf) {
                int row  = mf * 16 + ln;
                int byte = row * 256 + ((ks * 64 + g * 16) ^ ((row & 7) << 4));
                bf16x8 b = *(const bf16x8*)(As + byte);
                #pragma unroll
                for (int ci = 0; ci < 4; ++ci)
                    acc[mf][ci] = __builtin_amdgcn_mfma_f32_16x16x32_bf16(
                        af[ks][ci], b, acc[mf][ci], 0, 0, 0);
            }
        }

        // ---- pack acc (+bias) -> Cb, swizzled ----
        #pragma unroll
        for (int mf = 0; mf < 4; ++mf) {
            int node = mf * 16 + ln;
            #pragma unroll
            for (int ci = 0; ci < 4; ++ci) {
                int col = c0 + ci * 16 + g * 4;
                uint2 w;
                w.x = pack2(acc[mf][ci][0] + bias[ci].x,
                            acc[mf][ci][1] + bias[ci].y);
                w.y = pack2(acc[mf][ci][2] + bias[ci].z,
                            acc[mf][ci][3] + bias[ci].w);
                *(uint2*)(Cb + node * 512 + ((col * 2) ^ ((node & 7) << 4))) = w;
            }
        }
        __syncthreads();   // Cb complete; all waves done reading As

        // ---- coalesced C store: 512B contiguous per node row ----
        {
            int m0 = t * BM;
            int chunk = tid & 31;          // 16B chunk within 512B row
            int nb    = tid >> 5;
            #pragma unroll
            for (int it = 0; it < 8; ++it) {
                int node = it * 8 + nb;
                uint4 v = *(const uint4*)(Cb + node * 512 +
                                          ((chunk * 16) ^ ((node & 7) << 4)));
                if (m0 + node < M)
                    *(uint4*)(PQ + (size_t)(m0 + node) * 256 + chunk * 8) = v;
            }
        }

        // ---- stage next tile into As (waits only the z loads) ----
        if (have) {
            #pragma unroll
            for (int i = 0; i < 8; ++i) {
                int ci = tid + i * 256, row = ci >> 5, c4 = ci & 31;
                ushort4 b;
                b.x = f2bf(r[i].x); b.y = f2bf(r[i].y);
                b.z = f2bf(r[i].z); b.w = f2bf(r[i].w);
                *(ushort4*)(As + row * 256 + ((c4 * 8) ^ ((row & 7) << 4))) = b;
            }
        } else {
            break;
        }
        __syncthreads();   // As staged, Cb readback done, before next pack
        t = next;
    }
}

// ---------------------------------------------------------------------------
// Edge kernel: out[e] = relu(P[s] + Q[d]) . W2 + b2  (b1 pre-folded into P).
// 16 lanes x 4 edges per thread: 8 independent 16B gathers in flight.
// Bound by L2-miss random-gather service (~3.3 TB/s for ~150 MB misses);
// sorting can't beat it: relu(P+Q) is non-separable, one side stays random.
// ---------------------------------------------------------------------------
__global__ __launch_bounds__(256) void edge_mlp(
    const int* __restrict__ ei,    // [2][E] int32
    const u16* __restrict__ PQ,    // [M][256] bf16 (P = first 128, Q = last)
    const float* __restrict__ W2,  // [128]
    const float* __restrict__ b2,  // [1]
    float* __restrict__ out,       // [E]
    int E)
{
    int gid = blockIdx.x * 256 + threadIdx.x;
    int e0  = (gid >> 4) * 4;
    int sub = gid & 15;
    if (e0 >= E) return;

    float4 w2a = *(const float4*)(W2 + sub * 8);
    float4 w2b = *(const float4*)(W2 + sub * 8 + 4);
    float ww[8] = {w2a.x, w2a.y, w2a.z, w2a.w, w2b.x, w2b.y, w2b.z, w2b.w};
    float bias = b2[0];

    if (e0 + 3 < E) {
        int4 s = *(const int4*)(ei + e0);
        int4 d = *(const int4*)(ei + E + e0);
        uint4 p0 = *(const uint4*)(PQ + (size_t)s.x * 256 + sub * 8);
        uint4 p1 = *(const uint4*)(PQ + (size_t)s.y * 256 + sub * 8);
        uint4 p2 = *(const uint4*)(PQ + (size_t)s.z * 256 + sub * 8);
        uint4 p3 = *(const uint4*)(PQ + (size_t)s.w * 256 + sub * 8);
        uint4 q0 = *(const uint4*)(PQ + (size_t)d.x * 256 + 128 + sub * 8);
        uint4 q1 = *(const uint4*)(PQ + (size_t)d.y * 256 + 128 + sub * 8);
        uint4 q2 = *(const uint4*)(PQ + (size_t)d.z * 256 + 128 + sub * 8);
        uint4 q3 = *(const uint4*)(PQ + (size_t)d.w * 256 + 128 + sub * 8);

        float a0 = 0.f, a1 = 0.f, a2 = 0.f, a3 = 0.f;
        const u16* pu0 = (const u16*)&p0; const u16* qu0 = (const u16*)&q0;
        const u16* pu1 = (const u16*)&p1; const u16* qu1 = (const u16*)&q1;
        const u16* pu2 = (const u16*)&p2; const u16* qu2 = (const u16*)&q2;
        const u16* pu3 = (const u16*)&p3; const u16* qu3 = (const u16*)&q3;
        #pragma unroll
        for (int j = 0; j < 8; ++j) {
            a0 = fmaf(fmaxf(bf2f(pu0[j]) + bf2f(qu0[j]), 0.f), ww[j], a0);
            a1 = fmaf(fmaxf(bf2f(pu1[j]) + bf2f(qu1[j]), 0.f), ww[j], a1);
            a2 = fmaf(fmaxf(bf2f(pu2[j]) + bf2f(qu2[j]), 0.f), ww[j], a2);
            a3 = fmaf(fmaxf(bf2f(pu3[j]) + bf2f(qu3[j]), 0.f), ww[j], a3);
        }
        #pragma unroll
        for (int m = 1; m < 16; m <<= 1) {
            a0 += __shfl_xor(a0, m);
            a1 += __shfl_xor(a1, m);
            a2 += __shfl_xor(a2, m);
            a3 += __shfl_xor(a3, m);
        }
        if (sub == 0) {
            float4 o = make_float4(a0 + bias, a1 + bias, a2 + bias, a3 + bias);
            *(float4*)(out + e0) = o;
        }
    } else {
        for (int k = 0; k < 4; ++k) {
            int e = e0 + k;
            if (e >= E) break;
            int sn = ei[e], dn = ei[E + e];
            uint4 p = *(const uint4*)(PQ + (size_t)sn * 256 + sub * 8);
            uint4 q = *(const uint4*)(PQ + (size_t)dn * 256 + 128 + sub * 8);
            const u16* pu = (const u16*)&p; const u16* qu = (const u16*)&q;
            float acc = 0.f;
            #pragma unroll
            for (int j = 0; j < 8; ++j)
                acc = fmaf(fmaxf(bf2f(pu[j]) + bf2f(qu[j]), 0.f), ww[j], acc);
            #pragma unroll
            for (int m = 1; m < 16; m <<= 1) acc += __shfl_xor(acc, m);
            if (sub == 0) out[e] = acc + bias;
        }
    }
}

// ---------------------------------------------------------------------------
extern "C" void kernel_launch(void* const* d_in, const int* in_sizes, int n_in,
                              void* d_out, int out_size, void* d_ws, size_t ws_size,
                              hipStream_t stream) {
    const float* z  = (const float*)d_in[0];
    const int*   ei = (const int*)d_in[1];
    const float* W1 = (const float*)d_in[2];
    const float* b1 = (const float*)d_in[3];
    const float* W2 = (const float*)d_in[4];
    const float* b2 = (const float*)d_in[5];
    float* out = (float*)d_out;

    const int M = in_sizes[0] / 128;   // 100000 nodes
    const int E = in_sizes[1] / 2;     // 640000 edges

    u16* PQ = (u16*)d_ws;              // M*256*2 B = 51.2 MB

    int ntiles = (M + BM - 1) / BM;
    int gb = ntiles < 512 ? ntiles : 512;
    hipLaunchKernelGGL(node_gemm, dim3(gb), dim3(256), 0, stream,
                       z, W1, b1, PQ, M, ntiles);

    int eb = ((E + 3) / 4 * 16 + 255) / 256;
    hipLaunchKernelGGL(edge_mlp, dim3(eb), dim3(256), 0, stream,
                       ei, PQ, W2, b2, out, E);
}